// Round 7
// baseline (596.451 us; speedup 1.0000x reference)
//
#include <hip/hip_runtime.h>
#include <hip/hip_bf16.h>

#define B_  8
#define T_  4096
#define D_  1024
#define H_  16
#define DH_ 64
#define NC_ 4          // T-chunks in k_pv

typedef __bf16 bf8 __attribute__((ext_vector_type(8)));
typedef float f32x4 __attribute__((ext_vector_type(4)));

__device__ __forceinline__ unsigned short f2bf_rn(float f) {
    unsigned u = __float_as_uint(f);
    unsigned r = (u + 0x7FFF + ((u >> 16) & 1)) >> 16;
    return (unsigned short)r;
}

__device__ __forceinline__ void async_load16(const void* gp, void* lp) {
    __builtin_amdgcn_global_load_lds(
        (const __attribute__((address_space(1))) unsigned*)(gp),
        (__attribute__((address_space(3))) unsigned*)(lp), 16, 0, 0);
}

// ---------------- fused prep: xb cvt | Wv cvt | Qtb pad-zero | sel build ----------------
// grid: 16384 (xb) + 512 (Wv) + nzp (zpad) + 1 (sel)
__global__ void k_prep(const float* __restrict__ x, short* __restrict__ xb,
                       const float* __restrict__ Wv, short* __restrict__ Wvb,
                       short* __restrict__ Qtb, const int* __restrict__ idx,
                       int* __restrict__ sel, int U, int HU, int MP, int nzp) {
    int g = blockIdx.x;
    int tid = threadIdx.x;
    if (g < 16896) {
        const float* src = (g < 16384) ? x : Wv;
        short* dst = (g < 16384) ? xb : Wvb;
        size_t gg = (g < 16384) ? g : (g - 16384);
        size_t i = (gg * 256 + tid) * 8;
        float4 a = *(const float4*)(src + i);
        float4 b = *(const float4*)(src + i + 4);
        short4 s0, s1;
        s0.x = (short)f2bf_rn(a.x); s0.y = (short)f2bf_rn(a.y);
        s0.z = (short)f2bf_rn(a.z); s0.w = (short)f2bf_rn(a.w);
        s1.x = (short)f2bf_rn(b.x); s1.y = (short)f2bf_rn(b.y);
        s1.z = (short)f2bf_rn(b.z); s1.w = (short)f2bf_rn(b.w);
        *(short4*)(dst + i) = s0;
        *(short4*)(dst + i + 4) = s1;
    } else if (g < 16896 + nzp) {
        int bi = g - 16896;
        int npad = MP - HU;
        int b = bi / npad, r = bi - b * npad;
        short4 z = {0, 0, 0, 0};
        *(short4*)(Qtb + ((size_t)b * MP + HU + r) * D_ + tid * 4) = z;
    } else {
        for (int t = tid; t < T_; t += 256) sel[t] = 0;
        __syncthreads();
        if (tid < U) sel[idx[tid]] = tid + 1;
    }
}

// ---------------- fp32 tiled projection (gather-fused variant for Q) ----------------
// C[r][n] = sum_k x[b][idx[i]][k] * W[n][k].  grid (ceil(BU/64), 16)
__global__ __launch_bounds__(256) void k_projg(const float* __restrict__ x,
                                               const int* __restrict__ idx,
                                               const float* __restrict__ W,
                                               float* __restrict__ C, int U) {
    __shared__ float As[32][64 + 4];
    __shared__ float Bs[32][64 + 4];
    __shared__ int sidx[64];
    int M = B_ * U;
    if (threadIdx.x < U) sidx[threadIdx.x] = idx[threadIdx.x];
    __syncthreads();
    int m0 = blockIdx.x * 64, n0 = blockIdx.y * 64;
    int tid = threadIdx.x;
    int lr = tid >> 3, lc = (tid & 7) * 4;
    int ty = tid >> 4, tx = tid & 15;
    float acc[4][4] = {{0.f}};
    for (int k0 = 0; k0 < D_; k0 += 32) {
#pragma unroll
        for (int half = 0; half < 2; ++half) {
            int r = lr + half * 32;
            int gm = m0 + r;
            float4 v = make_float4(0.f, 0.f, 0.f, 0.f);
            if (gm < M) {
                int b = gm / U, i = gm - b * U;
                v = *(const float4*)(x + ((size_t)(b * T_ + sidx[i])) * D_ + k0 + lc);
            }
            As[lc + 0][r] = v.x; As[lc + 1][r] = v.y; As[lc + 2][r] = v.z; As[lc + 3][r] = v.w;
            int gn = n0 + r;
            float4 w = *(const float4*)(W + (size_t)gn * D_ + k0 + lc);
            Bs[lc + 0][r] = w.x; Bs[lc + 1][r] = w.y; Bs[lc + 2][r] = w.z; Bs[lc + 3][r] = w.w;
        }
        __syncthreads();
#pragma unroll
        for (int kk = 0; kk < 32; ++kk) {
            float4 a = *(const float4*)&As[kk][ty * 4];
            float4 bb = *(const float4*)&Bs[kk][tx * 4];
            acc[0][0] += a.x * bb.x; acc[0][1] += a.x * bb.y; acc[0][2] += a.x * bb.z; acc[0][3] += a.x * bb.w;
            acc[1][0] += a.y * bb.x; acc[1][1] += a.y * bb.y; acc[1][2] += a.y * bb.z; acc[1][3] += a.y * bb.w;
            acc[2][0] += a.z * bb.x; acc[2][1] += a.z * bb.y; acc[2][2] += a.z * bb.z; acc[2][3] += a.z * bb.w;
            acc[3][0] += a.w * bb.x; acc[3][1] += a.w * bb.y; acc[3][2] += a.w * bb.z; acc[3][3] += a.w * bb.w;
        }
        __syncthreads();
    }
#pragma unroll
    for (int i = 0; i < 4; ++i) {
        int gm = m0 + ty * 4 + i;
        if (gm < M)
            *(float4*)(C + (size_t)gm * D_ + n0 + tx * 4) =
                make_float4(acc[i][0], acc[i][1], acc[i][2], acc[i][3]);
    }
}

// ---------------- fp32 tiled projection with bias (Yr) ----------------
__global__ __launch_bounds__(256) void k_proj(const float* __restrict__ A,
                                              const float* __restrict__ W,
                                              const float* __restrict__ bias,
                                              float* __restrict__ C, int M) {
    __shared__ float As[32][64 + 4];
    __shared__ float Bs[32][64 + 4];
    int m0 = blockIdx.x * 64, n0 = blockIdx.y * 64;
    int tid = threadIdx.x;
    int lr = tid >> 3, lc = (tid & 7) * 4;
    int ty = tid >> 4, tx = tid & 15;
    float acc[4][4] = {{0.f}};
    for (int k0 = 0; k0 < D_; k0 += 32) {
#pragma unroll
        for (int half = 0; half < 2; ++half) {
            int r = lr + half * 32;
            int gm = m0 + r;
            float4 v = make_float4(0.f, 0.f, 0.f, 0.f);
            if (gm < M) v = *(const float4*)(A + (size_t)gm * D_ + k0 + lc);
            As[lc + 0][r] = v.x; As[lc + 1][r] = v.y; As[lc + 2][r] = v.z; As[lc + 3][r] = v.w;
            int gn = n0 + r;
            float4 w = *(const float4*)(W + (size_t)gn * D_ + k0 + lc);
            Bs[lc + 0][r] = w.x; Bs[lc + 1][r] = w.y; Bs[lc + 2][r] = w.z; Bs[lc + 3][r] = w.w;
        }
        __syncthreads();
#pragma unroll
        for (int kk = 0; kk < 32; ++kk) {
            float4 a = *(const float4*)&As[kk][ty * 4];
            float4 bb = *(const float4*)&Bs[kk][tx * 4];
            acc[0][0] += a.x * bb.x; acc[0][1] += a.x * bb.y; acc[0][2] += a.x * bb.z; acc[0][3] += a.x * bb.w;
            acc[1][0] += a.y * bb.x; acc[1][1] += a.y * bb.y; acc[1][2] += a.y * bb.z; acc[1][3] += a.y * bb.w;
            acc[2][0] += a.z * bb.x; acc[2][1] += a.z * bb.y; acc[2][2] += a.z * bb.z; acc[2][3] += a.z * bb.w;
            acc[3][0] += a.w * bb.x; acc[3][1] += a.w * bb.y; acc[3][2] += a.w * bb.z; acc[3][3] += a.w * bb.w;
        }
        __syncthreads();
    }
#pragma unroll
    for (int i = 0; i < 4; ++i) {
        int gm = m0 + ty * 4 + i;
        if (gm < M) {
            int gn = n0 + tx * 4;
            float4 v = make_float4(acc[i][0], acc[i][1], acc[i][2], acc[i][3]);
            if (bias) {
                v.x += bias[gn + 0]; v.y += bias[gn + 1];
                v.z += bias[gn + 2]; v.w += bias[gn + 3];
            }
            *(float4*)(C + (size_t)gm * D_ + gn) = v;
        }
    }
}

// ---------------- per-head Qt GEMM (writes bf16, 0.125-scaled) ----------------
__global__ __launch_bounds__(256) void k_qth(const float* __restrict__ Qs,
                                             const float* __restrict__ Wk,
                                             short* __restrict__ Qtb, int U, int MP) {
    __shared__ float As[32][64 + 4];
    __shared__ float Bs[32][64 + 4];
    int h = blockIdx.z;
    int m0 = blockIdx.x * 64, n0 = blockIdx.y * 64;
    int BU = B_ * U;
    int tid = threadIdx.x;
    int lr = tid >> 3, lc = (tid & 7) * 4;
    int ty = tid >> 4, tx = tid & 15;
    float acc[4][4] = {{0.f}};
    for (int k0 = 0; k0 < DH_; k0 += 32) {
#pragma unroll
        for (int half = 0; half < 2; ++half) {
            int r = lr + half * 32;
            int gm = m0 + r;
            float4 v = make_float4(0.f, 0.f, 0.f, 0.f);
            if (gm < BU) v = *(const float4*)(Qs + (size_t)gm * D_ + h * DH_ + k0 + lc);
            As[lc + 0][r] = v.x; As[lc + 1][r] = v.y; As[lc + 2][r] = v.z; As[lc + 3][r] = v.w;
            int kr = (tid >> 4) + half * 16;
            int nc = (tid & 15) * 4;
            float4 w = *(const float4*)(Wk + ((size_t)(h * DH_ + k0 + kr)) * D_ + n0 + nc);
            *(float4*)&Bs[kr][nc] = w;
        }
        __syncthreads();
#pragma unroll
        for (int kk = 0; kk < 32; ++kk) {
            float4 a = *(const float4*)&As[kk][ty * 4];
            float4 bb = *(const float4*)&Bs[kk][tx * 4];
            acc[0][0] += a.x * bb.x; acc[0][1] += a.x * bb.y; acc[0][2] += a.x * bb.z; acc[0][3] += a.x * bb.w;
            acc[1][0] += a.y * bb.x; acc[1][1] += a.y * bb.y; acc[1][2] += a.y * bb.z; acc[1][3] += a.y * bb.w;
            acc[2][0] += a.z * bb.x; acc[2][1] += a.z * bb.y; acc[2][2] += a.z * bb.z; acc[2][3] += a.z * bb.w;
            acc[3][0] += a.w * bb.x; acc[3][1] += a.w * bb.y; acc[3][2] += a.w * bb.z; acc[3][3] += a.w * bb.w;
        }
        __syncthreads();
    }
#pragma unroll
    for (int i = 0; i < 4; ++i) {
        int gm = m0 + ty * 4 + i;
        if (gm < BU) {
            int b = gm / U, ii = gm - b * U;
            short4 s;
            s.x = (short)f2bf_rn(0.125f * acc[i][0]);
            s.y = (short)f2bf_rn(0.125f * acc[i][1]);
            s.z = (short)f2bf_rn(0.125f * acc[i][2]);
            s.w = (short)f2bf_rn(0.125f * acc[i][3]);
            *(short4*)(Qtb + ((size_t)b * MP + h * U + ii) * D_ + n0 + tx * 4) = s;
        }
    }
}

// ---------------- fused: V GEMM (g<2048) | scores+exp GEMM (g>=2048) ----------------
__global__ __launch_bounds__(256) void k_scores_v(const short* __restrict__ Qtb,
                                                  const short* __restrict__ xb,
                                                  const short* __restrict__ Wvb,
                                                  short* __restrict__ attnb,
                                                  short* __restrict__ Vt, int MP) {
    __shared__ short smem[8192];          // 16 KB
    short* As = smem;
    short* Bs = smem + 4096;
    int g = blockIdx.x;
    int tid = threadIdx.x;
    int lane = tid & 63, w = tid >> 6;
    int wr = w >> 1, wc = w & 1;
    int quad = lane >> 4, l15 = lane & 15;
    const int K = D_;

    f32x4 acc[4][4];
#pragma unroll
    for (int mi = 0; mi < 4; ++mi)
#pragma unroll
        for (int ni = 0; ni < 4; ++ni)
            acc[mi][ni] = (f32x4){0.f, 0.f, 0.f, 0.f};

    int arow = wr * 64 + l15;
    int brow = wc * 64 + l15;
    int koff = quad * 8;

    if (g < 2048) {
        // ---- V: Vt[(b*H+h)*64+dh][t] = bf16( xb @ Wvb^T ), XCD keeps A-panel
        int mr = g & 7, n = (g >> 3) & 7, mq = g >> 6;
        int m = mq * 8 + mr;
        const short* Ab = xb + (size_t)m * 128 * K;
        const short* Bb = Wvb + (size_t)n * 128 * K;
        for (int kt = 0; kt < K; kt += 32) {
#pragma unroll
            for (int i = 0; i < 2; ++i) {
                int li = i * 256 + tid;
                int row = li >> 2, kc = (li & 3) << 3;
                async_load16(Ab + (size_t)row * K + kt + kc, As + li * 8);
                async_load16(Bb + (size_t)row * K + kt + kc, Bs + li * 8);
            }
            __syncthreads();
            bf8 af[4], bfr[4];
#pragma unroll
            for (int mi = 0; mi < 4; ++mi)
                af[mi] = *(const bf8*)(As + (arow + mi * 16) * 32 + koff);
#pragma unroll
            for (int ni = 0; ni < 4; ++ni)
                bfr[ni] = *(const bf8*)(Bs + (brow + ni * 16) * 32 + koff);
#pragma unroll
            for (int mi = 0; mi < 4; ++mi)
#pragma unroll
                for (int ni = 0; ni < 4; ++ni)
                    acc[mi][ni] = __builtin_amdgcn_mfma_f32_16x16x32_bf16(af[mi], bfr[ni], acc[mi][ni], 0, 0, 0);
            __syncthreads();
        }
        // epilogue: per-wave LDS transpose, packed writes, no barriers (ep is wave-private)
        int b = m >> 5;
        int tG0 = (m & 31) * 128 + wr * 64;
        int h = n * 2 + wc;
        short* ep = smem + w * 2048;
        const int PITCH = 80;             // 160 B rows: 16B-aligned b128 reads
#pragma unroll
        for (int ni = 0; ni < 4; ++ni) {
#pragma unroll
            for (int mi = 0; mi < 4; ++mi) {
                short4 s;
                s.x = (short)f2bf_rn(acc[mi][ni][0]);
                s.y = (short)f2bf_rn(acc[mi][ni][1]);
                s.z = (short)f2bf_rn(acc[mi][ni][2]);
                s.w = (short)f2bf_rn(acc[mi][ni][3]);
                *(short4*)(ep + l15 * PITCH + mi * 16 + quad * 4) = s;
            }
#pragma unroll
            for (int it = 0; it < 2; ++it) {
                int dhl = it * 8 + (lane >> 3);
                int seg = lane & 7;
                bf8 v = *(const bf8*)(ep + dhl * PITCH + seg * 8);
                int dh = ni * 16 + dhl;
                *(bf8*)(Vt + ((size_t)(b * H_ + h) * DH_ + dh) * T_ + tG0 + seg * 8) = v;
            }
        }
    } else {
        // ---- scores: attnb = exp(Qtb @ xb^T) bf16 (swapped operands -> t-contiguous stores)
        int gs = g - 2048;
        int n8 = (gs >> 3) & 3;
        int m = (gs >> 5) % 6;
        int b = (gs >> 5) / 6;
        int n = (gs & 7) + 8 * n8;
        const short* Ab = Qtb + (size_t)b * MP * K;
        const short* Bb = xb + (size_t)b * T_ * K;
        short* Cb = attnb + (size_t)b * MP * T_;
        int m0 = m * 128, n0 = n * 128;
        for (int kt = 0; kt < K; kt += 32) {
#pragma unroll
            for (int i = 0; i < 2; ++i) {
                int li = i * 256 + tid;
                int row = li >> 2, kc = (li & 3) << 3;
                async_load16(Ab + (size_t)(m0 + row) * K + kt + kc, As + li * 8);
                async_load16(Bb + (size_t)(n0 + row) * K + kt + kc, Bs + li * 8);
            }
            __syncthreads();
            bf8 af[4], bfr[4];
#pragma unroll
            for (int mi = 0; mi < 4; ++mi)
                af[mi] = *(const bf8*)(As + (arow + mi * 16) * 32 + koff);
#pragma unroll
            for (int ni = 0; ni < 4; ++ni)
                bfr[ni] = *(const bf8*)(Bs + (brow + ni * 16) * 32 + koff);
            // swapped: rows <- t (xb), cols <- q-rows (Qtb); acc[mi][ni] holds (ni=t-frag? no: first op bfr)
#pragma unroll
            for (int ni = 0; ni < 4; ++ni)
#pragma unroll
                for (int mi = 0; mi < 4; ++mi)
                    acc[ni][mi] = __builtin_amdgcn_mfma_f32_16x16x32_bf16(bfr[ni], af[mi], acc[ni][mi], 0, 0, 0);
            __syncthreads();
        }
#pragma unroll
        for (int ni = 0; ni < 4; ++ni)
#pragma unroll
            for (int mi = 0; mi < 4; ++mi) {
                int grow = m0 + wr * 64 + mi * 16 + l15;          // attnb row (q)
                int col = n0 + wc * 64 + ni * 16 + quad * 4;      // t
                short4 s;
                s.x = (short)f2bf_rn(__expf(acc[ni][mi][0]));
                s.y = (short)f2bf_rn(__expf(acc[ni][mi][1]));
                s.z = (short)f2bf_rn(__expf(acc[ni][mi][2]));
                s.w = (short)f2bf_rn(__expf(acc[ni][mi][3]));
                *(short4*)(Cb + (size_t)grow * T_ + col) = s;
            }
    }
}

// ---------------- PV flash: O_partial, rs_partial per (b,h,chunk) ----------------
__global__ __launch_bounds__(256) void k_pv(const short* __restrict__ attnb,
                                            const short* __restrict__ Vt,
                                            float* __restrict__ Op,
                                            float* __restrict__ rsp,
                                            int U, int MP) {
    __shared__ short vt[64 * 136];
    int gid = blockIdx.x;
    int c = gid & (NC_ - 1);
    int bh = gid >> 2;
    int h = bh & (H_ - 1);
    int b = bh >> 4;
    int tid = threadIdx.x;
    int lane = tid & 63, w = tid >> 6;
    int quad = lane >> 4;
    const short* Arow = attnb + ((size_t)b * MP + h * U) * T_;
    const short* Vrow = Vt + (size_t)bh * DH_ * T_;

    f32x4 O[3];
#pragma unroll
    for (int mi = 0; mi < 3; ++mi) O[mi] = (f32x4){0.f, 0.f, 0.f, 0.f};
    float rs[3] = {0.f, 0.f, 0.f};

    for (int tt = 0; tt < (T_ / NC_) / 128; ++tt) {
        int t0 = c * (T_ / NC_) + tt * 128;
#pragma unroll
        for (int it = 0; it < 4; ++it) {
            int idx = it * 256 + tid;
            int dh = idx >> 4, seg = idx & 15;
            bf8 v = *(const bf8*)(Vrow + (size_t)dh * T_ + t0 + seg * 8);
            *(bf8*)(vt + dh * 136 + seg * 8) = v;
        }
        __syncthreads();
        bf8 af[3][4];
#pragma unroll
        for (int mi = 0; mi < 3; ++mi)
#pragma unroll
            for (int kf = 0; kf < 4; ++kf)
                af[mi][kf] = *(const bf8*)(Arow + (size_t)(mi * 16 + (lane & 15)) * T_ + t0 + kf * 32 + quad * 8);
        if (w == 0) {
#pragma unroll
            for (int mi = 0; mi < 3; ++mi)
#pragma unroll
                for (int kf = 0; kf < 4; ++kf)
#pragma unroll
                    for (int j = 0; j < 8; ++j) rs[mi] += (float)af[mi][kf][j];
        }
#pragma unroll
        for (int kf = 0; kf < 4; ++kf) {
            bf8 bfr = *(const bf8*)(vt + (w * 16 + (lane & 15)) * 136 + kf * 32 + quad * 8);
#pragma unroll
            for (int mi = 0; mi < 3; ++mi)
                O[mi] = __builtin_amdgcn_mfma_f32_16x16x32_bf16(af[mi][kf], bfr, O[mi], 0, 0, 0);
        }
        __syncthreads();
    }
#pragma unroll
    for (int mi = 0; mi < 3; ++mi)
#pragma unroll
        for (int r = 0; r < 4; ++r)
            Op[((size_t)gid * 48 + mi * 16 + quad * 4 + r) * DH_ + w * 16 + (lane & 15)] = O[mi][r];
    if (w == 0) {
#pragma unroll
        for (int mi = 0; mi < 3; ++mi) {
            rs[mi] += __shfl_xor(rs[mi], 16);
            rs[mi] += __shfl_xor(rs[mi], 32);
            if (quad == 0) rsp[(size_t)gid * 48 + mi * 16 + lane] = rs[mi];
        }
    }
}

// ---------------- reduce chunks, normalize, assemble R ----------------
__global__ __launch_bounds__(256) void k_rows2(const float* __restrict__ Op,
                                               const float* __restrict__ rsp,
                                               float* __restrict__ R, int U) {
    __shared__ float inv[48];
    __shared__ float msum[4][64];
    int bh = blockIdx.x;
    int b = bh >> 4, h = bh & (H_ - 1);
    int tid = threadIdx.x;
    if (tid < 48) {
        float s = 0.f;
        for (int cc = 0; cc < NC_; ++cc) s += rsp[(size_t)(bh * NC_ + cc) * 48 + tid];
        inv[tid] = 1.f / s;
    }
    __syncthreads();
    int dh = tid & 63, ig = tid >> 6;
    float acc = 0.f;
    for (int p = 0; p < 11; ++p) {
        int i = p * 4 + ig;
        if (i < U) {
            float o = 0.f;
            for (int cc = 0; cc < NC_; ++cc)
                o += Op[((size_t)(bh * NC_ + cc) * 48 + i) * DH_ + dh];
            float v = o * inv[i];
            R[((size_t)b * (U + 1) + 1 + i) * D_ + h * DH_ + dh] = v;
            acc += v;
        }
    }
    msum[ig][dh] = acc;
    __syncthreads();
    if (ig == 0)
        R[((size_t)b * (U + 1)) * D_ + h * DH_ + dh] =
            (msum[0][dh] + msum[1][dh] + msum[2][dh] + msum[3][dh]) / (float)U;
}

// y[b][t][:] = Yr[b][sel[t]][:]
__global__ __launch_bounds__(256) void k_fill(const float* __restrict__ Yr,
                                              const int* __restrict__ sel,
                                              float* __restrict__ y, int U) {
    int blk = blockIdx.x;
    int b = blk >> 12, t = blk & (T_ - 1);
    int j = sel[t];
    const float4* src = (const float4*)(Yr + ((size_t)b * (U + 1) + j) * D_);
    float4* dst = (float4*)(y + (size_t)blk * D_);
    dst[threadIdx.x] = src[threadIdx.x];
}

extern "C" void kernel_launch(void* const* d_in, const int* in_sizes, int n_in,
                              void* d_out, int out_size, void* d_ws, size_t ws_size,
                              hipStream_t stream) {
    const float* x  = (const float*)d_in[0];
    const float* Wq = (const float*)d_in[1];
    const float* Wk = (const float*)d_in[2];
    const float* Wv = (const float*)d_in[3];
    const float* Wo = (const float*)d_in[4];
    const float* bo = (const float*)d_in[5];
    const int*  idx = (const int*)d_in[6];
    int U = in_sizes[6];                      // 41
    int HU = H_ * U;                          // 656
    int MP = ((HU + 127) / 128) * 128;        // 768
    int nzp = B_ * (MP - HU);

    char* w = (char*)d_ws;
    auto alloc = [&](size_t bytes) { char* p = w; w += (bytes + 255) & ~(size_t)255; return p; };

    float* Qs    = (float*)alloc((size_t)B_ * U * D_ * 4);
    short* Qtb   = (short*)alloc((size_t)B_ * MP * D_ * 2);
    short* xb    = (short*)alloc((size_t)B_ * T_ * D_ * 2);
    short* Wvb   = (short*)alloc((size_t)D_ * D_ * 2);
    short* attnb = (short*)alloc((size_t)B_ * MP * T_ * 2);
    short* Vtb   = (short*)alloc((size_t)B_ * D_ * T_ * 2);
    float* Opb   = (float*)alloc((size_t)B_ * H_ * NC_ * 48 * DH_ * 4);
    float* rspb  = (float*)alloc((size_t)B_ * H_ * NC_ * 48 * 4);
    float* R     = (float*)alloc((size_t)B_ * (U + 1) * D_ * 4);
    float* Yr    = (float*)alloc((size_t)B_ * (U + 1) * D_ * 4);
    int*   sel   = (int*)alloc((size_t)T_ * 4);

    k_prep<<<dim3(16896 + nzp + 1), dim3(256), 0, stream>>>(x, xb, Wv, Wvb, Qtb, idx, sel, U, HU, MP, nzp);
    k_projg<<<dim3((B_ * U + 63) / 64, D_ / 64), dim3(256), 0, stream>>>(x, idx, Wq, Qs, U);
    k_qth<<<dim3((B_ * U + 63) / 64, D_ / 64, H_), dim3(256), 0, stream>>>(Qs, Wk, Qtb, U, MP);
    k_scores_v<<<dim3(2048 + 8 * 4 * 6 * B_), dim3(256), 0, stream>>>(Qtb, xb, Wvb, attnb, Vtb, MP);
    k_pv<<<dim3(B_ * H_ * NC_), dim3(256), 0, stream>>>(attnb, Vtb, Opb, rspb, U, MP);
    k_rows2<<<dim3(B_ * H_), dim3(256), 0, stream>>>(Opb, rspb, R, U);
    k_proj<<<dim3((B_ * (U + 1) + 63) / 64, D_ / 64), dim3(256), 0, stream>>>(R, Wo, bo, Yr, B_ * (U + 1));
    k_fill<<<dim3(B_ * T_), dim3(256), 0, stream>>>(Yr, sel, (float*)d_out, U);
}

// Round 8
// 593.605 us; speedup vs baseline: 1.0048x; 1.0048x over previous
//
#include <hip/hip_runtime.h>
#include <hip/hip_bf16.h>

#define B_  8
#define T_  4096
#define D_  1024
#define H_  16
#define DH_ 64

typedef __bf16 bf8 __attribute__((ext_vector_type(8)));
typedef float f32x4 __attribute__((ext_vector_type(4)));

__device__ __forceinline__ unsigned short f2bf_rn(float f) {
    unsigned u = __float_as_uint(f);
    unsigned r = (u + 0x7FFF + ((u >> 16) & 1)) >> 16;
    return (unsigned short)r;
}

__device__ __forceinline__ void async_load16(const void* gp, void* lp) {
    __builtin_amdgcn_global_load_lds(
        (const __attribute__((address_space(1))) unsigned*)(gp),
        (__attribute__((address_space(3))) unsigned*)(lp), 16, 0, 0);
}

// ---------------- fused prep: xb cvt | Wv cvt | Qtb pad-zero | sel build ----------------
__global__ void k_prep(const float* __restrict__ x, short* __restrict__ xb,
                       const float* __restrict__ Wv, short* __restrict__ Wvb,
                       short* __restrict__ Qtb, const int* __restrict__ idx,
                       int* __restrict__ sel, int U, int HU, int MP, int nzp) {
    int g = blockIdx.x;
    int tid = threadIdx.x;
    if (g < 16896) {
        const float* src = (g < 16384) ? x : Wv;
        short* dst = (g < 16384) ? xb : Wvb;
        size_t gg = (g < 16384) ? g : (g - 16384);
        size_t i = (gg * 256 + tid) * 8;
        float4 a = *(const float4*)(src + i);
        float4 b = *(const float4*)(src + i + 4);
        short4 s0, s1;
        s0.x = (short)f2bf_rn(a.x); s0.y = (short)f2bf_rn(a.y);
        s0.z = (short)f2bf_rn(a.z); s0.w = (short)f2bf_rn(a.w);
        s1.x = (short)f2bf_rn(b.x); s1.y = (short)f2bf_rn(b.y);
        s1.z = (short)f2bf_rn(b.z); s1.w = (short)f2bf_rn(b.w);
        *(short4*)(dst + i) = s0;
        *(short4*)(dst + i + 4) = s1;
    } else if (g < 16896 + nzp) {
        int bi = g - 16896;
        int npad = MP - HU;
        int b = bi / npad, r = bi - b * npad;
        short4 z = {0, 0, 0, 0};
        *(short4*)(Qtb + ((size_t)b * MP + HU + r) * D_ + tid * 4) = z;
    } else {
        for (int t = tid; t < T_; t += 256) sel[t] = 0;
        __syncthreads();
        if (tid < U) sel[idx[tid]] = tid + 1;
    }
}

// ---------------- fp32 tiled projection (gather-fused variant for Q) ----------------
__global__ __launch_bounds__(256) void k_projg(const float* __restrict__ x,
                                               const int* __restrict__ idx,
                                               const float* __restrict__ W,
                                               float* __restrict__ C, int U) {
    __shared__ float As[32][64 + 4];
    __shared__ float Bs[32][64 + 4];
    __shared__ int sidx[64];
    int M = B_ * U;
    if (threadIdx.x < U) sidx[threadIdx.x] = idx[threadIdx.x];
    __syncthreads();
    int m0 = blockIdx.x * 64, n0 = blockIdx.y * 64;
    int tid = threadIdx.x;
    int lr = tid >> 3, lc = (tid & 7) * 4;
    int ty = tid >> 4, tx = tid & 15;
    float acc[4][4] = {{0.f}};
    for (int k0 = 0; k0 < D_; k0 += 32) {
#pragma unroll
        for (int half = 0; half < 2; ++half) {
            int r = lr + half * 32;
            int gm = m0 + r;
            float4 v = make_float4(0.f, 0.f, 0.f, 0.f);
            if (gm < M) {
                int b = gm / U, i = gm - b * U;
                v = *(const float4*)(x + ((size_t)(b * T_ + sidx[i])) * D_ + k0 + lc);
            }
            As[lc + 0][r] = v.x; As[lc + 1][r] = v.y; As[lc + 2][r] = v.z; As[lc + 3][r] = v.w;
            int gn = n0 + r;
            float4 w = *(const float4*)(W + (size_t)gn * D_ + k0 + lc);
            Bs[lc + 0][r] = w.x; Bs[lc + 1][r] = w.y; Bs[lc + 2][r] = w.z; Bs[lc + 3][r] = w.w;
        }
        __syncthreads();
#pragma unroll
        for (int kk = 0; kk < 32; ++kk) {
            float4 a = *(const float4*)&As[kk][ty * 4];
            float4 bb = *(const float4*)&Bs[kk][tx * 4];
            acc[0][0] += a.x * bb.x; acc[0][1] += a.x * bb.y; acc[0][2] += a.x * bb.z; acc[0][3] += a.x * bb.w;
            acc[1][0] += a.y * bb.x; acc[1][1] += a.y * bb.y; acc[1][2] += a.y * bb.z; acc[1][3] += a.y * bb.w;
            acc[2][0] += a.z * bb.x; acc[2][1] += a.z * bb.y; acc[2][2] += a.z * bb.z; acc[2][3] += a.z * bb.w;
            acc[3][0] += a.w * bb.x; acc[3][1] += a.w * bb.y; acc[3][2] += a.w * bb.z; acc[3][3] += a.w * bb.w;
        }
        __syncthreads();
    }
#pragma unroll
    for (int i = 0; i < 4; ++i) {
        int gm = m0 + ty * 4 + i;
        if (gm < M)
            *(float4*)(C + (size_t)gm * D_ + n0 + tx * 4) =
                make_float4(acc[i][0], acc[i][1], acc[i][2], acc[i][3]);
    }
}

// ---------------- fp32 tiled projection with bias (Yr) ----------------
__global__ __launch_bounds__(256) void k_proj(const float* __restrict__ A,
                                              const float* __restrict__ W,
                                              const float* __restrict__ bias,
                                              float* __restrict__ C, int M) {
    __shared__ float As[32][64 + 4];
    __shared__ float Bs[32][64 + 4];
    int m0 = blockIdx.x * 64, n0 = blockIdx.y * 64;
    int tid = threadIdx.x;
    int lr = tid >> 3, lc = (tid & 7) * 4;
    int ty = tid >> 4, tx = tid & 15;
    float acc[4][4] = {{0.f}};
    for (int k0 = 0; k0 < D_; k0 += 32) {
#pragma unroll
        for (int half = 0; half < 2; ++half) {
            int r = lr + half * 32;
            int gm = m0 + r;
            float4 v = make_float4(0.f, 0.f, 0.f, 0.f);
            if (gm < M) v = *(const float4*)(A + (size_t)gm * D_ + k0 + lc);
            As[lc + 0][r] = v.x; As[lc + 1][r] = v.y; As[lc + 2][r] = v.z; As[lc + 3][r] = v.w;
            int gn = n0 + r;
            float4 w = *(const float4*)(W + (size_t)gn * D_ + k0 + lc);
            Bs[lc + 0][r] = w.x; Bs[lc + 1][r] = w.y; Bs[lc + 2][r] = w.z; Bs[lc + 3][r] = w.w;
        }
        __syncthreads();
#pragma unroll
        for (int kk = 0; kk < 32; ++kk) {
            float4 a = *(const float4*)&As[kk][ty * 4];
            float4 bb = *(const float4*)&Bs[kk][tx * 4];
            acc[0][0] += a.x * bb.x; acc[0][1] += a.x * bb.y; acc[0][2] += a.x * bb.z; acc[0][3] += a.x * bb.w;
            acc[1][0] += a.y * bb.x; acc[1][1] += a.y * bb.y; acc[1][2] += a.y * bb.z; acc[1][3] += a.y * bb.w;
            acc[2][0] += a.z * bb.x; acc[2][1] += a.z * bb.y; acc[2][2] += a.z * bb.z; acc[2][3] += a.z * bb.w;
            acc[3][0] += a.w * bb.x; acc[3][1] += a.w * bb.y; acc[3][2] += a.w * bb.z; acc[3][3] += a.w * bb.w;
        }
        __syncthreads();
    }
#pragma unroll
    for (int i = 0; i < 4; ++i) {
        int gm = m0 + ty * 4 + i;
        if (gm < M) {
            int gn = n0 + tx * 4;
            float4 v = make_float4(acc[i][0], acc[i][1], acc[i][2], acc[i][3]);
            if (bias) {
                v.x += bias[gn + 0]; v.y += bias[gn + 1];
                v.z += bias[gn + 2]; v.w += bias[gn + 3];
            }
            *(float4*)(C + (size_t)gm * D_ + gn) = v;
        }
    }
}

// ---------------- per-head Qt GEMM (writes bf16, 0.125-scaled) ----------------
__global__ __launch_bounds__(256) void k_qth(const float* __restrict__ Qs,
                                             const float* __restrict__ Wk,
                                             short* __restrict__ Qtb, int U, int MP) {
    __shared__ float As[32][64 + 4];
    __shared__ float Bs[32][64 + 4];
    int h = blockIdx.z;
    int m0 = blockIdx.x * 64, n0 = blockIdx.y * 64;
    int BU = B_ * U;
    int tid = threadIdx.x;
    int lr = tid >> 3, lc = (tid & 7) * 4;
    int ty = tid >> 4, tx = tid & 15;
    float acc[4][4] = {{0.f}};
    for (int k0 = 0; k0 < DH_; k0 += 32) {
#pragma unroll
        for (int half = 0; half < 2; ++half) {
            int r = lr + half * 32;
            int gm = m0 + r;
            float4 v = make_float4(0.f, 0.f, 0.f, 0.f);
            if (gm < BU) v = *(const float4*)(Qs + (size_t)gm * D_ + h * DH_ + k0 + lc);
            As[lc + 0][r] = v.x; As[lc + 1][r] = v.y; As[lc + 2][r] = v.z; As[lc + 3][r] = v.w;
            int kr = (tid >> 4) + half * 16;
            int nc = (tid & 15) * 4;
            float4 w = *(const float4*)(Wk + ((size_t)(h * DH_ + k0 + kr)) * D_ + n0 + nc);
            *(float4*)&Bs[kr][nc] = w;
        }
        __syncthreads();
#pragma unroll
        for (int kk = 0; kk < 32; ++kk) {
            float4 a = *(const float4*)&As[kk][ty * 4];
            float4 bb = *(const float4*)&Bs[kk][tx * 4];
            acc[0][0] += a.x * bb.x; acc[0][1] += a.x * bb.y; acc[0][2] += a.x * bb.z; acc[0][3] += a.x * bb.w;
            acc[1][0] += a.y * bb.x; acc[1][1] += a.y * bb.y; acc[1][2] += a.y * bb.z; acc[1][3] += a.y * bb.w;
            acc[2][0] += a.z * bb.x; acc[2][1] += a.z * bb.y; acc[2][2] += a.z * bb.z; acc[2][3] += a.z * bb.w;
            acc[3][0] += a.w * bb.x; acc[3][1] += a.w * bb.y; acc[3][2] += a.w * bb.z; acc[3][3] += a.w * bb.w;
        }
        __syncthreads();
    }
#pragma unroll
    for (int i = 0; i < 4; ++i) {
        int gm = m0 + ty * 4 + i;
        if (gm < BU) {
            int b = gm / U, ii = gm - b * U;
            short4 s;
            s.x = (short)f2bf_rn(0.125f * acc[i][0]);
            s.y = (short)f2bf_rn(0.125f * acc[i][1]);
            s.z = (short)f2bf_rn(0.125f * acc[i][2]);
            s.w = (short)f2bf_rn(0.125f * acc[i][3]);
            *(short4*)(Qtb + ((size_t)b * MP + h * U + ii) * D_ + n0 + tx * 4) = s;
        }
    }
}

// ---------------- fused: V GEMM (g<2048) | scores+exp GEMM (g>=2048), batch-local XCD swizzle ----------------
__global__ __launch_bounds__(256) void k_scores_v(const short* __restrict__ Qtb,
                                                  const short* __restrict__ xb,
                                                  const short* __restrict__ Wvb,
                                                  short* __restrict__ attnb,
                                                  short* __restrict__ Vt, int MP) {
    __shared__ short smem[8192];          // 16 KB
    short* As = smem;
    short* Bs = smem + 4096;
    int g = blockIdx.x;
    int tid = threadIdx.x;
    int lane = tid & 63, w = tid >> 6;
    int wr = w >> 1, wc = w & 1;
    int quad = lane >> 4, l15 = lane & 15;
    const int K = D_;

    f32x4 acc[4][4];
#pragma unroll
    for (int mi = 0; mi < 4; ++mi)
#pragma unroll
        for (int ni = 0; ni < 4; ++ni)
            acc[mi][ni] = (f32x4){0.f, 0.f, 0.f, 0.f};

    int arow = wr * 64 + l15;
    int brow = wc * 64 + l15;
    int koff = quad * 8;

    if (g < 2048) {
        // ---- V half: b = g&7 keeps each batch's xb on one XCD
        int b = g & 7;
        int n = (g >> 3) & 7;
        int mq = g >> 6;                  // 0..31 t-tile within batch
        const short* Ab = xb + (size_t)(b * 32 + mq) * 128 * K;
        const short* Bb = Wvb + (size_t)n * 128 * K;
        for (int kt = 0; kt < K; kt += 32) {
#pragma unroll
            for (int i = 0; i < 2; ++i) {
                int li = i * 256 + tid;
                int row = li >> 2, kc = (li & 3) << 3;
                async_load16(Ab + (size_t)row * K + kt + kc, As + li * 8);
                async_load16(Bb + (size_t)row * K + kt + kc, Bs + li * 8);
            }
            __syncthreads();
            bf8 af[4], bfr[4];
#pragma unroll
            for (int mi = 0; mi < 4; ++mi)
                af[mi] = *(const bf8*)(As + (arow + mi * 16) * 32 + koff);
#pragma unroll
            for (int ni = 0; ni < 4; ++ni)
                bfr[ni] = *(const bf8*)(Bs + (brow + ni * 16) * 32 + koff);
#pragma unroll
            for (int mi = 0; mi < 4; ++mi)
#pragma unroll
                for (int ni = 0; ni < 4; ++ni)
                    acc[mi][ni] = __builtin_amdgcn_mfma_f32_16x16x32_bf16(af[mi], bfr[ni], acc[mi][ni], 0, 0, 0);
            __syncthreads();
        }
        // per-wave LDS transpose epilogue (wave-private buffer, no barriers)
        int tG0 = mq * 128 + wr * 64;
        int h = n * 2 + wc;
        short* ep = smem + w * 2048;
        const int PITCH = 72;             // 144 B rows: 16B-aligned, 2-way banks
#pragma unroll
        for (int ni = 0; ni < 4; ++ni) {
#pragma unroll
            for (int mi = 0; mi < 4; ++mi) {
                short4 s;
                s.x = (short)f2bf_rn(acc[mi][ni][0]);
                s.y = (short)f2bf_rn(acc[mi][ni][1]);
                s.z = (short)f2bf_rn(acc[mi][ni][2]);
                s.w = (short)f2bf_rn(acc[mi][ni][3]);
                *(short4*)(ep + l15 * PITCH + mi * 16 + quad * 4) = s;
            }
#pragma unroll
            for (int it = 0; it < 2; ++it) {
                int dhl = it * 8 + (lane >> 3);
                int seg = lane & 7;
                bf8 v = *(const bf8*)(ep + dhl * PITCH + seg * 8);
                int dh = ni * 16 + dhl;
                *(bf8*)(Vt + ((size_t)(b * H_ + h) * DH_ + dh) * T_ + tG0 + seg * 8) = v;
            }
        }
    } else {
        // ---- scores half: b = gs&7 (same XCD as the V half of batch b)
        int gs = g - 2048;
        int b = gs & 7;
        int r2 = gs >> 3;                 // 0..191
        int m = r2 % 6;
        int n = r2 / 6;                   // 0..31
        const short* Ab = Qtb + (size_t)b * MP * K;
        const short* Bb = xb + (size_t)b * T_ * K;
        short* Cb = attnb + (size_t)b * MP * T_;
        int m0 = m * 128, n0 = n * 128;
        for (int kt = 0; kt < K; kt += 32) {
#pragma unroll
            for (int i = 0; i < 2; ++i) {
                int li = i * 256 + tid;
                int row = li >> 2, kc = (li & 3) << 3;
                async_load16(Ab + (size_t)(m0 + row) * K + kt + kc, As + li * 8);
                async_load16(Bb + (size_t)(n0 + row) * K + kt + kc, Bs + li * 8);
            }
            __syncthreads();
            bf8 af[4], bfr[4];
#pragma unroll
            for (int mi = 0; mi < 4; ++mi)
                af[mi] = *(const bf8*)(As + (arow + mi * 16) * 32 + koff);
#pragma unroll
            for (int ni = 0; ni < 4; ++ni)
                bfr[ni] = *(const bf8*)(Bs + (brow + ni * 16) * 32 + koff);
#pragma unroll
            for (int ni = 0; ni < 4; ++ni)
#pragma unroll
                for (int mi = 0; mi < 4; ++mi)
                    acc[ni][mi] = __builtin_amdgcn_mfma_f32_16x16x32_bf16(bfr[ni], af[mi], acc[ni][mi], 0, 0, 0);
            __syncthreads();
        }
#pragma unroll
        for (int ni = 0; ni < 4; ++ni)
#pragma unroll
            for (int mi = 0; mi < 4; ++mi) {
                int grow = m0 + wr * 64 + mi * 16 + l15;
                int col = n0 + wc * 64 + ni * 16 + quad * 4;
                short4 s;
                s.x = (short)f2bf_rn(__expf(acc[ni][mi][0]));
                s.y = (short)f2bf_rn(__expf(acc[ni][mi][1]));
                s.z = (short)f2bf_rn(__expf(acc[ni][mi][2]));
                s.w = (short)f2bf_rn(__expf(acc[ni][mi][3]));
                *(short4*)(Cb + (size_t)grow * T_ + col) = s;
            }
    }
}

// ---------------- PV as staged GEMM: O^T(64x48) = Vt_h(64xT) . P_h^T(Tx48), fused rs + R assembly ----------------
// grid B*H (128 blocks). Both operands t-contiguous -> coalesced staging.
#define VPITCH 136   // 128 + 8 shorts: 2-way-free frag reads
__global__ __launch_bounds__(256) void k_pvT(const short* __restrict__ attnb,
                                             const short* __restrict__ Vt,
                                             float* __restrict__ R, int U, int MP) {
    __shared__ short sm[(64 + 48) * VPITCH];       // 30464 B staging (vs | ps)
    __shared__ float redbuf[64 * 48];              // 12 KB O^T accumulator
    __shared__ float inv[48];
    short* vs = sm;
    short* ps = sm + 64 * VPITCH;
    int gid = blockIdx.x;
    int h = gid & (H_ - 1), b = gid >> 4;
    int tid = threadIdx.x, lane = tid & 63, w = tid >> 6;
    int l15 = lane & 15, quad = lane >> 4;
    const short* Pg = attnb + ((size_t)b * MP + h * U) * T_;   // 48 rows (tail rows harmless)
    const short* Vg = Vt + ((size_t)(b * H_ + h)) * DH_ * T_;

    f32x4 acc[4][3];
#pragma unroll
    for (int mf = 0; mf < 4; ++mf)
#pragma unroll
        for (int nf = 0; nf < 3; ++nf)
            acc[mf][nf] = (f32x4){0.f, 0.f, 0.f, 0.f};
    float rspart = 0.f;

    int vrow = tid >> 2, vseg = tid & 3;           // 64 rows x 4 thr (64 B each)

    for (int kt = 0; kt < T_; kt += 128) {
        {   // stage V tile 64x128
            const short* src = Vg + (size_t)vrow * T_ + kt + vseg * 32;
            short* d = vs + vrow * VPITCH + vseg * 32;
            bf8 v0 = *(const bf8*)(src);
            bf8 v1 = *(const bf8*)(src + 8);
            bf8 v2 = *(const bf8*)(src + 16);
            bf8 v3 = *(const bf8*)(src + 24);
            *(bf8*)(d) = v0; *(bf8*)(d + 8) = v1; *(bf8*)(d + 16) = v2; *(bf8*)(d + 24) = v3;
        }
        if (tid < 192) {  // stage P tile 48x128 + accumulate row-sums
            const short* src = Pg + (size_t)vrow * T_ + kt + vseg * 32;
            short* d = ps + vrow * VPITCH + vseg * 32;
            bf8 v0 = *(const bf8*)(src);
            bf8 v1 = *(const bf8*)(src + 8);
            bf8 v2 = *(const bf8*)(src + 16);
            bf8 v3 = *(const bf8*)(src + 24);
            *(bf8*)(d) = v0; *(bf8*)(d + 8) = v1; *(bf8*)(d + 16) = v2; *(bf8*)(d + 24) = v3;
#pragma unroll
            for (int j = 0; j < 8; ++j)
                rspart += (float)v0[j] + (float)v1[j] + (float)v2[j] + (float)v3[j];
        }
        __syncthreads();
        // wave w takes K-slice w*32 of the 128
        bf8 af[4], bfr[3];
#pragma unroll
        for (int mf = 0; mf < 4; ++mf)
            af[mf] = *(const bf8*)(vs + (mf * 16 + l15) * VPITCH + w * 32 + quad * 8);
#pragma unroll
        for (int nf = 0; nf < 3; ++nf)
            bfr[nf] = *(const bf8*)(ps + (nf * 16 + l15) * VPITCH + w * 32 + quad * 8);
#pragma unroll
        for (int mf = 0; mf < 4; ++mf)
#pragma unroll
            for (int nf = 0; nf < 3; ++nf)
                acc[mf][nf] = __builtin_amdgcn_mfma_f32_16x16x32_bf16(af[mf], bfr[nf], acc[mf][nf], 0, 0, 0);
        __syncthreads();
    }

    // cross-wave O^T reduce into redbuf (C-layout: dh = mf*16+quad*4+r, q = nf*16+l15)
    for (int wv = 0; wv < 4; ++wv) {
        if (w == wv) {
#pragma unroll
            for (int mf = 0; mf < 4; ++mf)
#pragma unroll
                for (int nf = 0; nf < 3; ++nf)
#pragma unroll
                    for (int r = 0; r < 4; ++r) {
                        int i2 = (mf * 16 + quad * 4 + r) * 48 + nf * 16 + l15;
                        if (wv == 0) redbuf[i2] = acc[mf][nf][r];
                        else redbuf[i2] += acc[mf][nf][r];
                    }
        }
        __syncthreads();
    }
    // rs partials -> inv (reuse sm as float scratch; staging reads are done)
    float* rsf = (float*)sm;
    if (tid < 192) rsf[tid] = rspart;
    __syncthreads();
    if (tid < 48)
        inv[tid] = 1.f / (rsf[tid * 4] + rsf[tid * 4 + 1] + rsf[tid * 4 + 2] + rsf[tid * 4 + 3]);
    __syncthreads();
    // normalize + write R rows (1+i) and mean row 0 (h-slice)
    int dh = tid >> 2, part = tid & 3;
    float msum = 0.f;
#pragma unroll
    for (int j = 0; j < 12; ++j) {
        int q = part * 12 + j;
        if (q < U) {
            float v = redbuf[dh * 48 + q] * inv[q];
            R[((size_t)b * (U + 1) + 1 + q) * D_ + h * DH_ + dh] = v;
            msum += v;
        }
    }
    msum += __shfl_down(msum, 1);
    msum += __shfl_down(msum, 2);
    if (part == 0)
        R[((size_t)b * (U + 1)) * D_ + h * DH_ + dh] = msum / (float)U;
}

// y[b][t][:] = Yr[b][sel[t]][:]
__global__ __launch_bounds__(256) void k_fill(const float* __restrict__ Yr,
                                              const int* __restrict__ sel,
                                              float* __restrict__ y, int U) {
    int blk = blockIdx.x;
    int b = blk >> 12, t = blk & (T_ - 1);
    int j = sel[t];
    const float4* src = (const float4*)(Yr + ((size_t)b * (U + 1) + j) * D_);
    float4* dst = (float4*)(y + (size_t)blk * D_);
    dst[threadIdx.x] = src[threadIdx.x];
}

extern "C" void kernel_launch(void* const* d_in, const int* in_sizes, int n_in,
                              void* d_out, int out_size, void* d_ws, size_t ws_size,
                              hipStream_t stream) {
    const float* x  = (const float*)d_in[0];
    const float* Wq = (const float*)d_in[1];
    const float* Wk = (const float*)d_in[2];
    const float* Wv = (const float*)d_in[3];
    const float* Wo = (const float*)d_in[4];
    const float* bo = (const float*)d_in[5];
    const int*  idx = (const int*)d_in[6];
    int U = in_sizes[6];                      // 41
    int HU = H_ * U;                          // 656
    int MP = ((HU + 127) / 128) * 128;        // 768
    int nzp = B_ * (MP - HU);

    char* w = (char*)d_ws;
    auto alloc = [&](size_t bytes) { char* p = w; w += (bytes + 255) & ~(size_t)255; return p; };

    float* Qs    = (float*)alloc((size_t)B_ * U * D_ * 4);
    short* Qtb   = (short*)alloc((size_t)B_ * MP * D_ * 2);
    short* xb    = (short*)alloc((size_t)B_ * T_ * D_ * 2);
    short* Wvb   = (short*)alloc((size_t)D_ * D_ * 2);
    short* attnb = (short*)alloc((size_t)B_ * MP * T_ * 2);
    short* Vtb   = (short*)alloc((size_t)B_ * D_ * T_ * 2);
    float* R     = (float*)alloc((size_t)B_ * (U + 1) * D_ * 4);
    float* Yr    = (float*)alloc((size_t)B_ * (U + 1) * D_ * 4);
    int*   sel   = (int*)alloc((size_t)T_ * 4);

    k_prep<<<dim3(16896 + nzp + 1), dim3(256), 0, stream>>>(x, xb, Wv, Wvb, Qtb, idx, sel, U, HU, MP, nzp);
    k_projg<<<dim3((B_ * U + 63) / 64, D_ / 64), dim3(256), 0, stream>>>(x, idx, Wq, Qs, U);
    k_qth<<<dim3((B_ * U + 63) / 64, D_ / 64, H_), dim3(256), 0, stream>>>(Qs, Wk, Qtb, U, MP);
    k_scores_v<<<dim3(2048 + 1536), dim3(256), 0, stream>>>(Qtb, xb, Wvb, attnb, Vtb, MP);
    k_pvT<<<dim3(B_ * H_), dim3(256), 0, stream>>>(attnb, Vtb, R, U, MP);
    k_proj<<<dim3((B_ * (U + 1) + 63) / 64, D_ / 64), dim3(256), 0, stream>>>(R, Wo, bo, Yr, B_ * (U + 1));
    k_fill<<<dim3(B_ * T_), dim3(256), 0, stream>>>(Yr, sel, (float*)d_out, U);
}